// Round 11
// baseline (317.575 us; speedup 1.0000x reference)
//
#include <hip/hip_runtime.h>
#include <hip/hip_fp16.h>

#define FD 128    // hidden feature dim
#define OD 64     // output dim
#define KC 8      // privatized histogram copies for deg_out (k = blockIdx&7 = XCD id)
#define RN 256    // nodes per region (dst >> 8)
#define CHUNKS 256
#define NRMAX 1024

typedef _Float16 f16x8 __attribute__((ext_vector_type(8)));
typedef float    f32x4 __attribute__((ext_vector_type(4)));

// ---------------- misc ----------------

__global__ void zero_kernel(int* __restrict__ a, int n) {
    int i = blockIdx.x * 256 + threadIdx.x;
    if (i < n) a[i] = 0;
}

// fill with sentinel (-1), int4 stores (n divisible by 4)
__global__ void fill_neg_kernel(int* __restrict__ a, int n4) {
    int i = blockIdx.x * 256 + threadIdx.x;
    if (i < n4) ((int4*)a)[i] = make_int4(-1, -1, -1, -1);
}

// unpack 16-bit packed per-copy counters -> r_out
__global__ void rout_kernel(const int* __restrict__ cnt, float* __restrict__ r_out,
                            int N, int NW) {
    int v = blockIdx.x * 256 + threadIdx.x;
    if (v >= N) return;
    int word = v >> 1, sh = (v & 1) * 16;
    int s = 0;
    #pragma unroll
    for (int k = 0; k < KC; k++) s += (cnt[k * NW + word] >> sh) & 0xFFFF;
    r_out[v] = rsqrtf((float)max(s, 1));
}

// Xs(half) = r_out (row) * X ; one float4 -> 4 halves per thread
__global__ void prescale_kernel(const float* __restrict__ X, const float* __restrict__ r_out,
                                __half* __restrict__ Xs, int n4) {
    int i = blockIdx.x * 256 + threadIdx.x;
    if (i >= n4) return;
    int v = i >> 5;                    // 32 float4 per 128-float row
    float r = r_out[v];
    float4 t = ((const float4*)X)[i];
    __half2 h0 = __floats2half2_rn(t.x * r, t.y * r);
    __half2 h1 = __floats2half2_rn(t.z * r, t.w * r);
    ((__half2*)Xs)[2 * i]     = h0;
    ((__half2*)Xs)[2 * i + 1] = h1;
}

// ---------------- pass 1: partition edges by region (dst>>8) ----------------

__global__ __launch_bounds__(1024) void region_hist_kernel(const int* __restrict__ dst,
                                                           int* __restrict__ hist_g,
                                                           int E, int NR, int CS) {
    __shared__ int hist[NRMAX];
    int c = blockIdx.x;
    for (int t = threadIdx.x; t < NR; t += 1024) hist[t] = 0;
    __syncthreads();
    int e0 = c * CS, e1 = min(e0 + CS, E);
    int nv = (e1 - e0) & ~3;
    for (int e = e0 + threadIdx.x * 4; e < e0 + nv; e += 4096) {
        int4 d = *(const int4*)(dst + e);
        atomicAdd(&hist[d.x >> 8], 1);
        atomicAdd(&hist[d.y >> 8], 1);
        atomicAdd(&hist[d.z >> 8], 1);
        atomicAdd(&hist[d.w >> 8], 1);
    }
    for (int e = e0 + nv + threadIdx.x; e < e1; e += 1024)
        atomicAdd(&hist[dst[e] >> 8], 1);
    __syncthreads();
    for (int t = threadIdx.x; t < NR; t += 1024) hist_g[c * NR + t] = hist[t];
}

// dense scan (rstart) + PADDED scan (prstart) + padded per-chunk cursors (pcur).
// Each (chunk,region) run is padded to a multiple of 16 ints (64 B) so no cache
// line is ever shared between two partition blocks -> no cross-XCD false sharing.
__global__ __launch_bounds__(1024) void region_scan_kernel(const int* __restrict__ hist_g,
                                                           int* __restrict__ rstart,
                                                           int* __restrict__ prstart,
                                                           int* __restrict__ pcur,
                                                           int NR, int E) {
    __shared__ int wsum[16];
    int tid = threadIdx.x, lane = tid & 63, w = tid >> 6;
    int total = 0, ptotal = 0;
    if (tid < NR)
        for (int c = 0; c < CHUNKS; c++) {
            int h = hist_g[c * NR + tid];
            total += h;
            ptotal += (h + 15) & ~15;
        }
    // scan 1: dense totals
    int x = total;
    #pragma unroll
    for (int d = 1; d < 64; d <<= 1) {
        int t = __shfl_up(x, d, 64);
        if (lane >= d) x += t;
    }
    if (lane == 63) wsum[w] = x;
    __syncthreads();
    if (w == 0) {
        int s = (lane < 16) ? wsum[lane] : 0;
        #pragma unroll
        for (int d = 1; d < 16; d <<= 1) {
            int t = __shfl_up(s, d, 64);
            if (lane >= d) s += t;
        }
        if (lane < 16) wsum[lane] = s;
    }
    __syncthreads();
    int off = (w == 0) ? 0 : wsum[w - 1];
    if (tid < NR) rstart[tid] = x + off - total;
    if (tid == 0) rstart[NR] = E;
    __syncthreads();
    // scan 2: padded totals
    x = ptotal;
    #pragma unroll
    for (int d = 1; d < 64; d <<= 1) {
        int t = __shfl_up(x, d, 64);
        if (lane >= d) x += t;
    }
    if (lane == 63) wsum[w] = x;
    __syncthreads();
    if (w == 0) {
        int s = (lane < 16) ? wsum[lane] : 0;
        #pragma unroll
        for (int d = 1; d < 16; d <<= 1) {
            int t = __shfl_up(s, d, 64);
            if (lane >= d) s += t;
        }
        if (lane < 16) wsum[lane] = s;
    }
    __syncthreads();
    off = (w == 0) ? 0 : wsum[w - 1];
    if (tid < NR) {
        int pstart = x + off - ptotal;
        prstart[tid] = pstart;
        int run = pstart;
        for (int c = 0; c < CHUNKS; c++) {
            pcur[c * NR + tid] = run;
            run += (hist_g[c * NR + tid] + 15) & ~15;
        }
        if (tid == NR - 1) prstart[NR] = pstart + ptotal;
    }
}

// scatter packed edges ((dst&255)<<17 | src) into PADDED region runs via LDS cursors.
// 16-bit packed src histogram: cs[k][s>>1] += 1<<(16*(s&1)); k = blockIdx&7 (XCD-local).
__global__ __launch_bounds__(1024) void partition_kernel(const int* __restrict__ src,
                                                         const int* __restrict__ dst,
                                                         const int* __restrict__ pcur,
                                                         int* __restrict__ epack,
                                                         int* __restrict__ cnt_src,
                                                         int E, int NR, int CS, int NW) {
    __shared__ int cur[NRMAX];
    int c = blockIdx.x;
    int* __restrict__ cs = cnt_src + (size_t)(blockIdx.x & (KC - 1)) * NW;
    for (int t = threadIdx.x; t < NR; t += 1024) cur[t] = pcur[c * NR + t];
    __syncthreads();
    int e0 = c * CS, e1 = min(e0 + CS, E);
    int nv = (e1 - e0) & ~3;
    for (int e = e0 + threadIdx.x * 4; e < e0 + nv; e += 4096) {
        int4 d = *(const int4*)(dst + e);
        int4 s = *(const int4*)(src + e);
        int p0 = atomicAdd(&cur[d.x >> 8], 1);
        int p1 = atomicAdd(&cur[d.y >> 8], 1);
        int p2 = atomicAdd(&cur[d.z >> 8], 1);
        int p3 = atomicAdd(&cur[d.w >> 8], 1);
        epack[p0] = ((d.x & 255) << 17) | s.x;
        epack[p1] = ((d.y & 255) << 17) | s.y;
        epack[p2] = ((d.z & 255) << 17) | s.z;
        epack[p3] = ((d.w & 255) << 17) | s.w;
        atomicAdd(&cs[s.x >> 1], 1 << ((s.x & 1) * 16));
        atomicAdd(&cs[s.y >> 1], 1 << ((s.y & 1) * 16));
        atomicAdd(&cs[s.z >> 1], 1 << ((s.z & 1) * 16));
        atomicAdd(&cs[s.w >> 1], 1 << ((s.w & 1) * 16));
    }
    for (int e = e0 + nv + threadIdx.x; e < e1; e += 1024) {
        int d = dst[e], s = src[e];
        int pos = atomicAdd(&cur[d >> 8], 1);
        epack[pos] = ((d & 255) << 17) | s;
        atomicAdd(&cs[s >> 1], 1 << ((s & 1) * 16));
    }
}

// ---------------- pass 2: per-region LDS counting sort -> exact CSR ----------------
// Reads the PADDED range [prstart[r], prstart[r+1]) skipping sentinels (pk<0);
// writes dense csrc/row_start exactly as before.
__global__ __launch_bounds__(1024) void region_sort_kernel(const int* __restrict__ epack,
                                                           const int* __restrict__ rstart,
                                                           const int* __restrict__ prstart,
                                                           int* __restrict__ csrc,
                                                           int* __restrict__ row_start,
                                                           float* __restrict__ r_in,
                                                           int N, int NR, int E) {
    __shared__ int cnt[RN];
    __shared__ int cur[RN];
    __shared__ int wsum[16];
    const int r = blockIdx.x, tid = threadIdx.x;
    const int lane = tid & 63, w = tid >> 6;
    const int p0 = prstart[r], p1 = prstart[r + 1];
    const int s0 = rstart[r];
    if (tid < RN) cnt[tid] = 0;
    __syncthreads();
    for (int e = p0 + tid; e < p1; e += 1024) {
        int pk = epack[e];
        if (pk >= 0) atomicAdd(&cnt[pk >> 17], 1);
    }
    __syncthreads();
    int cv = (tid < RN) ? cnt[tid] : 0;
    int x = cv;
    #pragma unroll
    for (int d = 1; d < 64; d <<= 1) {
        int t = __shfl_up(x, d, 64);
        if (lane >= d) x += t;
    }
    if (lane == 63 && w < 4) wsum[w] = x;
    __syncthreads();
    if (tid < RN) {
        int woff = 0;
        for (int i = 0; i < w; i++) woff += wsum[i];
        int start = s0 + x - cv + woff;
        cur[tid] = start;
        int node = r * RN + tid;
        if (node < N) {
            row_start[node] = start;
            r_in[node] = rsqrtf((float)max(cv, 1));
        }
    }
    if (r == NR - 1 && tid == 0) row_start[N] = E;
    __syncthreads();
    for (int e = p0 + tid; e < p1; e += 1024) {
        int pk = epack[e];
        if (pk >= 0) {
            int pos = atomicAdd(&cur[pk >> 17], 1);
            csrc[pos] = pk & 0x1FFFF;
        }
    }
}

// ---------------- aggregation: one wave per node, CSR gather (fp16 rows) ----------------
// z1h[v] = fp16( r_in[v] * sum_e Xs[csrc[e]] )
__global__ __launch_bounds__(256) void agg128_kernel(const __half* __restrict__ Xs,
                                                     const float* __restrict__ r_in,
                                                     const int* __restrict__ rs,
                                                     const int* __restrict__ csrc,
                                                     __half* __restrict__ Z, int N) {
    const int lane = threadIdx.x & 63, wv = threadIdx.x >> 6;
    int v = blockIdx.x * 4 + wv;
    if (v >= N) return;
    int s0 = rs[v], s1 = rs[v + 1];
    float ax = 0.f, ay = 0.f;
    int e = s0;
    for (; e + 16 <= s1; e += 16) {
        int idx[16];
        #pragma unroll
        for (int u = 0; u < 16; u++) idx[u] = csrc[e + u];
        __half2 t[16];
        #pragma unroll
        for (int u = 0; u < 16; u++)
            t[u] = ((const __half2*)(Xs + (size_t)idx[u] * FD))[lane];
        #pragma unroll
        for (int u = 0; u < 16; u++) {
            float2 f = __half22float2(t[u]);
            ax += f.x; ay += f.y;
        }
    }
    for (; e + 4 <= s1; e += 4) {
        int idx[4];
        #pragma unroll
        for (int u = 0; u < 4; u++) idx[u] = csrc[e + u];
        __half2 t[4];
        #pragma unroll
        for (int u = 0; u < 4; u++)
            t[u] = ((const __half2*)(Xs + (size_t)idx[u] * FD))[lane];
        #pragma unroll
        for (int u = 0; u < 4; u++) {
            float2 f = __half22float2(t[u]);
            ax += f.x; ay += f.y;
        }
    }
    for (; e < s1; e++) {
        float2 f = __half22float2(((const __half2*)(Xs + (size_t)csrc[e] * FD))[lane]);
        ax += f.x; ay += f.y;
    }
    float ri = r_in[v];
    ((__half2*)(Z + (size_t)v * FD))[lane] = __floats2half2_rn(ax * ri, ay * ri);
}

// 2 nodes per wave, 32 lanes x half2 each (4B/lane loads, 128B/row)
__global__ __launch_bounds__(256) void agg64_kernel(const __half* __restrict__ T,
                                                    const float* __restrict__ r_in,
                                                    const int* __restrict__ rs,
                                                    const int* __restrict__ csrc,
                                                    const float* __restrict__ bc,
                                                    float* __restrict__ out, int N) {
    const int tid = threadIdx.x;
    const int lane = tid & 63, wv = tid >> 6;
    const int hf = lane >> 5, l32 = lane & 31;
    int v = blockIdx.x * 8 + wv * 2 + hf;
    if (v >= N) return;
    int s0 = rs[v], s1 = rs[v + 1];
    float ax = 0.f, ay = 0.f;
    int e = s0;
    for (; e + 8 <= s1; e += 8) {
        int idx[8];
        #pragma unroll
        for (int u = 0; u < 8; u++) idx[u] = csrc[e + u];
        __half2 t[8];
        #pragma unroll
        for (int u = 0; u < 8; u++)
            t[u] = ((const __half2*)(T + (size_t)idx[u] * OD))[l32];
        #pragma unroll
        for (int u = 0; u < 8; u++) {
            float2 f = __half22float2(t[u]);
            ax += f.x; ay += f.y;
        }
    }
    for (; e < s1; e++) {
        float2 f = __half22float2(((const __half2*)(T + (size_t)csrc[e] * OD))[l32]);
        ax += f.x; ay += f.y;
    }
    float ri = r_in[v];
    float2 o;
    o.x = ax * ri + bc[l32 * 2];
    o.y = ay * ri + bc[l32 * 2 + 1];
    ((float2*)(out + (size_t)v * OD))[l32] = o;
}

// ---------------- MFMA GEMM 1: y1h = fp16(relu(z1h@W1h + b1) * r_out) ----------------
__global__ __launch_bounds__(256) void gemm1_mfma_kernel(const __half* __restrict__ Ah,
                                                         const __half* __restrict__ Bh,
                                                         const float* __restrict__ b1,
                                                         const float* __restrict__ rowscale,
                                                         __half* __restrict__ Ch,
                                                         int M, int ntiles) {
    const int w = threadIdx.x >> 6, lane = threadIdx.x & 63;
    const int l15 = lane & 15, quad = lane >> 4;
    const _Float16* B = (const _Float16*)Bh;

    f16x8 bfrag[2][4];
    #pragma unroll
    for (int nt = 0; nt < 2; nt++) {
        int col = 32 * w + 16 * nt + l15;
        #pragma unroll
        for (int kk = 0; kk < 4; kk++) {
            int kb = kk * 32 + quad * 8;
            f16x8 bf;
            #pragma unroll
            for (int j = 0; j < 8; j++) bf[j] = B[(size_t)(kb + j) * FD + col];
            bfrag[nt][kk] = bf;
        }
    }

    for (int t = blockIdx.x; t < ntiles; t += gridDim.x) {
        int row0 = t * 16;
        const _Float16* Arow = (const _Float16*)Ah + (size_t)(row0 + l15) * FD + quad * 8;
        f16x8 afrag[4];
        #pragma unroll
        for (int kk = 0; kk < 4; kk++) afrag[kk] = *(const f16x8*)(Arow + kk * 32);
        f32x4 acc0 = {0.f, 0.f, 0.f, 0.f};
        f32x4 acc1 = {0.f, 0.f, 0.f, 0.f};
        #pragma unroll
        for (int kk = 0; kk < 4; kk++) {
            acc0 = __builtin_amdgcn_mfma_f32_16x16x32_f16(afrag[kk], bfrag[0][kk], acc0, 0, 0, 0);
            acc1 = __builtin_amdgcn_mfma_f32_16x16x32_f16(afrag[kk], bfrag[1][kk], acc1, 0, 0, 0);
        }
        int c0 = 32 * w + l15, c1 = c0 + 16;
        float bb0 = b1[c0], bb1 = b1[c1];
        #pragma unroll
        for (int r = 0; r < 4; r++) {
            int row = row0 + quad * 4 + r;
            if (row < M) {
                float rsc = rowscale[row];
                Ch[(size_t)row * FD + c0] = __float2half(fmaxf(acc0[r] + bb0, 0.f) * rsc);
                Ch[(size_t)row * FD + c1] = __float2half(fmaxf(acc1[r] + bb1, 0.f) * rsc);
            }
        }
    }
}

// ---------------- MFMA GEMM 2: tbuf = fp16(y1h @ Wch) (N=64) ----------------
__global__ __launch_bounds__(256) void gemm2_mfma_kernel(const __half* __restrict__ Ah,
                                                         const __half* __restrict__ Bh,
                                                         __half* __restrict__ Ch,
                                                         int M, int ntiles) {
    const int w = threadIdx.x >> 6, lane = threadIdx.x & 63;
    const int l15 = lane & 15, quad = lane >> 4;
    const _Float16* B = (const _Float16*)Bh;

    f16x8 bfrag[4];
    int col = 16 * w + l15;
    #pragma unroll
    for (int kk = 0; kk < 4; kk++) {
        int kb = kk * 32 + quad * 8;
        f16x8 bf;
        #pragma unroll
        for (int j = 0; j < 8; j++) bf[j] = B[(size_t)(kb + j) * OD + col];
        bfrag[kk] = bf;
    }

    for (int t = blockIdx.x; t < ntiles; t += gridDim.x) {
        int row0 = t * 16;
        const _Float16* Arow = (const _Float16*)Ah + (size_t)(row0 + l15) * FD + quad * 8;
        f16x8 afrag[4];
        #pragma unroll
        for (int kk = 0; kk < 4; kk++) afrag[kk] = *(const f16x8*)(Arow + kk * 32);
        f32x4 acc = {0.f, 0.f, 0.f, 0.f};
        #pragma unroll
        for (int kk = 0; kk < 4; kk++)
            acc = __builtin_amdgcn_mfma_f32_16x16x32_f16(afrag[kk], bfrag[kk], acc, 0, 0, 0);
        #pragma unroll
        for (int r = 0; r < 4; r++) {
            int row = row0 + quad * 4 + r;
            if (row < M)
                Ch[(size_t)row * OD + col] = __float2half(acc[r]);
        }
    }
}

// ---------------- fold: W1h = fp16(W1); Wch = fp16(W2@Wf); bc = b2@Wf + bf ----------------
__global__ void fold_kernel(const float* __restrict__ W2, const float* __restrict__ Wf,
                            const float* __restrict__ b2, const float* __restrict__ bf,
                            const float* __restrict__ W1,
                            __half* __restrict__ W1h, __half* __restrict__ Wch,
                            float* __restrict__ bc) {
    int idx = blockIdx.x * 256 + threadIdx.x;
    if (idx < FD * FD) W1h[idx] = __float2half(W1[idx]);
    if (idx < FD * OD) {
        int i = idx / OD, j = idx % OD;
        float s = 0.f;
        for (int k = 0; k < FD; k++) s += W2[i * FD + k] * Wf[k * OD + j];
        Wch[idx] = __float2half(s);
    }
    if (idx < OD) {
        float s = bf[idx];
        for (int k = 0; k < FD; k++) s += b2[k] * Wf[k * OD + idx];
        bc[idx] = s;
    }
}

// ---------------- launch ----------------
extern "C" void kernel_launch(void* const* d_in, const int* in_sizes, int n_in,
                              void* d_out, int out_size, void* d_ws, size_t ws_size,
                              hipStream_t stream) {
    const float* in_feat = (const float*)d_in[0];
    const int*   src     = (const int*)d_in[1];
    const int*   dst     = (const int*)d_in[2];
    const float* W1      = (const float*)d_in[3];
    const float* b1      = (const float*)d_in[4];
    const float* W2      = (const float*)d_in[5];
    const float* b2      = (const float*)d_in[6];
    const float* Wf      = (const float*)d_in[7];
    const float* bf      = (const float*)d_in[8];
    float* out = (float*)d_out;

    const int N = in_sizes[0] / FD;        // 50000
    const int E = in_sizes[1];             // 1600000
    const int NR = (N + RN - 1) / RN;      // 196 (<= NRMAX)
    const int NW = (N + 1) / 2;            // packed-counter words per copy
    const int CS = (((E + CHUNKS - 1) / CHUNKS) + 3) & ~3;  // 4-aligned for int4
    const int PEmax = E + CHUNKS * NR * 16; // padded epack upper bound (div by 4)

    char* ws = (char*)d_ws;
    size_t off = 0;
    auto alloc = [&](size_t bytes) -> void* {
        void* p = ws + off;
        off += (bytes + 255) / 256 * 256;
        return p;
    };
    // cnt_src (0.8 MB) + epack (9.6 MB) adjacent, both dead before gemm2 writes
    // tbuf (N*OD*2 = 6.4 MB) which aliases them.
    int*    cnt_src = (int*)alloc((size_t)KC * NW * 4);
    int*    epack   = (int*)alloc((size_t)PEmax * 4);
    __half* tbuf    = (__half*)cnt_src;
    float*  r_out   = (float*)alloc((size_t)N * 4);
    float*  r_in    = (float*)alloc((size_t)N * 4);
    int*    hist_g  = (int*)alloc((size_t)CHUNKS * NR * 4);
    int*    pcur    = (int*)alloc((size_t)CHUNKS * NR * 4);
    int*    rstart  = (int*)alloc((size_t)(NR + 1) * 4);
    int*    prstart = (int*)alloc((size_t)(NR + 1) * 4);
    int*    csrc    = (int*)alloc((size_t)E * 4);
    int*    row_start = (int*)alloc((size_t)(N + 1) * 4);
    __half* z1h     = (__half*)alloc((size_t)N * FD * 2);
    __half* y1h     = (__half*)alloc((size_t)N * FD * 2);
    __half* Xs      = (__half*)alloc((size_t)N * FD * 2);
    __half* W1h     = (__half*)alloc((size_t)FD * FD * 2);
    __half* Wch     = (__half*)alloc((size_t)FD * OD * 2);
    float*  bc      = (float*)alloc((size_t)OD * 4);
    (void)ws_size; (void)n_in; (void)out_size;

    const int gN = (N + 255) / 256;
    const int ntiles = (N + 15) / 16;      // 3125
    const int gemmgrid = ntiles < 1024 ? ntiles : 1024;

    // exact dst-sort: region partition (pass 1, padded runs) + per-region counting
    // sort (pass 2). pass 1 also builds the packed privatized src histogram.
    zero_kernel<<<(KC * NW + 255) / 256, 256, 0, stream>>>(cnt_src, KC * NW);
    fill_neg_kernel<<<(PEmax / 4 + 255) / 256, 256, 0, stream>>>(epack, PEmax / 4);
    region_hist_kernel<<<CHUNKS, 1024, 0, stream>>>(dst, hist_g, E, NR, CS);
    region_scan_kernel<<<1, 1024, 0, stream>>>(hist_g, rstart, prstart, pcur, NR, E);
    partition_kernel<<<CHUNKS, 1024, 0, stream>>>(src, dst, pcur, epack, cnt_src, E, NR, CS, NW);
    region_sort_kernel<<<NR, 1024, 0, stream>>>(epack, rstart, prstart, csrc, row_start, r_in, N, NR, E);
    rout_kernel<<<gN, 256, 0, stream>>>(cnt_src, r_out, N, NW);

    // fold weights (fp16) + combined final bias
    fold_kernel<<<(FD * FD + 255) / 256, 256, 0, stream>>>(W2, Wf, b2, bf, W1, W1h, Wch, bc);

    // layer 1: Xs = half(r_out*x) ; z1h = half(r_in*Agg(Xs))
    prescale_kernel<<<(N * 32 + 255) / 256, 256, 0, stream>>>(in_feat, r_out, Xs, N * 32);
    agg128_kernel<<<(N + 3) / 4, 256, 0, stream>>>(Xs, r_in, row_start, csrc, z1h, N);

    // MFMA GEMMs: y1h = relu(z1h@W1h+b1)*r_out ; tbuf = y1h@Wch
    gemm1_mfma_kernel<<<gemmgrid, 256, 0, stream>>>(z1h, W1h, b1, r_out, y1h, N, ntiles);
    gemm2_mfma_kernel<<<gemmgrid, 256, 0, stream>>>(y1h, Wch, tbuf, N, ntiles);

    // final: out = r_in*Agg(tbuf) + bc
    agg64_kernel<<<(N + 7) / 8, 256, 0, stream>>>(tbuf, r_in, row_start, csrc, bc, out, N);
}

// Round 12
// 281.965 us; speedup vs baseline: 1.1263x; 1.1263x over previous
//
#include <hip/hip_runtime.h>
#include <hip/hip_fp16.h>

#define FD 128    // hidden feature dim
#define OD 64     // output dim
#define RN 256    // nodes per region (id >> 8)
#define CHUNKS 256
#define NRMAX 1024

typedef _Float16 f16x8 __attribute__((ext_vector_type(8)));
typedef float    f32x4 __attribute__((ext_vector_type(4)));

// ---------------- misc ----------------

// Xs(half) = r_out (row) * X ; one float4 -> 4 halves per thread
__global__ void prescale_kernel(const float* __restrict__ X, const float* __restrict__ r_out,
                                __half* __restrict__ Xs, int n4) {
    int i = blockIdx.x * 256 + threadIdx.x;
    if (i >= n4) return;
    int v = i >> 5;                    // 32 float4 per 128-float row
    float r = r_out[v];
    float4 t = ((const float4*)X)[i];
    __half2 h0 = __floats2half2_rn(t.x * r, t.y * r);
    __half2 h1 = __floats2half2_rn(t.z * r, t.w * r);
    ((__half2*)Xs)[2 * i]     = h0;
    ((__half2*)Xs)[2 * i + 1] = h1;
}

// ---------------- pass 1: dual histograms by region (dst>>8 and src>>8) ----------------

__global__ __launch_bounds__(1024) void region_hist_kernel(const int* __restrict__ src,
                                                           const int* __restrict__ dst,
                                                           int* __restrict__ hist_g,
                                                           int* __restrict__ hist_gs,
                                                           int E, int NR, int CS) {
    __shared__ int hist[NRMAX];
    __shared__ int hist_s[NRMAX];
    int c = blockIdx.x;
    for (int t = threadIdx.x; t < NR; t += 1024) { hist[t] = 0; hist_s[t] = 0; }
    __syncthreads();
    int e0 = c * CS, e1 = min(e0 + CS, E);
    int nv = (e1 - e0) & ~3;
    for (int e = e0 + threadIdx.x * 4; e < e0 + nv; e += 4096) {
        int4 d = *(const int4*)(dst + e);
        int4 s = *(const int4*)(src + e);
        atomicAdd(&hist[d.x >> 8], 1);
        atomicAdd(&hist[d.y >> 8], 1);
        atomicAdd(&hist[d.z >> 8], 1);
        atomicAdd(&hist[d.w >> 8], 1);
        atomicAdd(&hist_s[s.x >> 8], 1);
        atomicAdd(&hist_s[s.y >> 8], 1);
        atomicAdd(&hist_s[s.z >> 8], 1);
        atomicAdd(&hist_s[s.w >> 8], 1);
    }
    for (int e = e0 + nv + threadIdx.x; e < e1; e += 1024) {
        atomicAdd(&hist[dst[e] >> 8], 1);
        atomicAdd(&hist_s[src[e] >> 8], 1);
    }
    __syncthreads();
    for (int t = threadIdx.x; t < NR; t += 1024) {
        hist_g[c * NR + t]  = hist[t];
        hist_gs[c * NR + t] = hist_s[t];
    }
}

// scans of region totals + per-chunk cursor tables for both partitions (1 block)
__global__ __launch_bounds__(1024) void region_scan_kernel(const int* __restrict__ hist_g,
                                                           const int* __restrict__ hist_gs,
                                                           int* __restrict__ rstart,
                                                           int* __restrict__ cursor,
                                                           int* __restrict__ sstart,
                                                           int* __restrict__ scursor,
                                                           int NR, int E) {
    __shared__ int wsum[16];
    int tid = threadIdx.x, lane = tid & 63, w = tid >> 6;
    // ---- scan 1: dst totals ----
    int total = 0;
    if (tid < NR)
        for (int c = 0; c < CHUNKS; c++) total += hist_g[c * NR + tid];
    int x = total;
    #pragma unroll
    for (int d = 1; d < 64; d <<= 1) {
        int t = __shfl_up(x, d, 64);
        if (lane >= d) x += t;
    }
    if (lane == 63) wsum[w] = x;
    __syncthreads();
    if (w == 0) {
        int s = (lane < 16) ? wsum[lane] : 0;
        #pragma unroll
        for (int d = 1; d < 16; d <<= 1) {
            int t = __shfl_up(s, d, 64);
            if (lane >= d) s += t;
        }
        if (lane < 16) wsum[lane] = s;
    }
    __syncthreads();
    int off = (w == 0) ? 0 : wsum[w - 1];
    if (tid < NR) {
        int start = x + off - total;
        rstart[tid] = start;
        int run = start;
        for (int c = 0; c < CHUNKS; c++) {
            cursor[c * NR + tid] = run;
            run += hist_g[c * NR + tid];
        }
    }
    if (tid == 0) rstart[NR] = E;
    __syncthreads();
    // ---- scan 2: src totals ----
    total = 0;
    if (tid < NR)
        for (int c = 0; c < CHUNKS; c++) total += hist_gs[c * NR + tid];
    x = total;
    #pragma unroll
    for (int d = 1; d < 64; d <<= 1) {
        int t = __shfl_up(x, d, 64);
        if (lane >= d) x += t;
    }
    if (lane == 63) wsum[w] = x;
    __syncthreads();
    if (w == 0) {
        int s = (lane < 16) ? wsum[lane] : 0;
        #pragma unroll
        for (int d = 1; d < 16; d <<= 1) {
            int t = __shfl_up(s, d, 64);
            if (lane >= d) s += t;
        }
        if (lane < 16) wsum[lane] = s;
    }
    __syncthreads();
    off = (w == 0) ? 0 : wsum[w - 1];
    if (tid < NR) {
        int start = x + off - total;
        sstart[tid] = start;
        int run = start;
        for (int c = 0; c < CHUNKS; c++) {
            scursor[c * NR + tid] = run;
            run += hist_gs[c * NR + tid];
        }
    }
    if (tid == 0) sstart[NR] = E;
}

// dual scatter via LDS cursors: epack=((dst&255)<<17|src) by dst-region,
// spack=(src&255) bytes by src-region. NO per-edge global atomics.
__global__ __launch_bounds__(1024) void partition_kernel(const int* __restrict__ src,
                                                         const int* __restrict__ dst,
                                                         const int* __restrict__ cursor,
                                                         const int* __restrict__ scursor,
                                                         int* __restrict__ epack,
                                                         unsigned char* __restrict__ spack,
                                                         int E, int NR, int CS) {
    __shared__ int cur[NRMAX];
    __shared__ int scur[NRMAX];
    int c = blockIdx.x;
    for (int t = threadIdx.x; t < NR; t += 1024) {
        cur[t]  = cursor[c * NR + t];
        scur[t] = scursor[c * NR + t];
    }
    __syncthreads();
    int e0 = c * CS, e1 = min(e0 + CS, E);
    int nv = (e1 - e0) & ~3;
    for (int e = e0 + threadIdx.x * 4; e < e0 + nv; e += 4096) {
        int4 d = *(const int4*)(dst + e);
        int4 s = *(const int4*)(src + e);
        int p0 = atomicAdd(&cur[d.x >> 8], 1);
        int p1 = atomicAdd(&cur[d.y >> 8], 1);
        int p2 = atomicAdd(&cur[d.z >> 8], 1);
        int p3 = atomicAdd(&cur[d.w >> 8], 1);
        epack[p0] = ((d.x & 255) << 17) | s.x;
        epack[p1] = ((d.y & 255) << 17) | s.y;
        epack[p2] = ((d.z & 255) << 17) | s.z;
        epack[p3] = ((d.w & 255) << 17) | s.w;
        int q0 = atomicAdd(&scur[s.x >> 8], 1);
        int q1 = atomicAdd(&scur[s.y >> 8], 1);
        int q2 = atomicAdd(&scur[s.z >> 8], 1);
        int q3 = atomicAdd(&scur[s.w >> 8], 1);
        spack[q0] = (unsigned char)(s.x & 255);
        spack[q1] = (unsigned char)(s.y & 255);
        spack[q2] = (unsigned char)(s.z & 255);
        spack[q3] = (unsigned char)(s.w & 255);
    }
    for (int e = e0 + nv + threadIdx.x; e < e1; e += 1024) {
        int d = dst[e], s = src[e];
        int pos = atomicAdd(&cur[d >> 8], 1);
        epack[pos] = ((d & 255) << 17) | s;
        int qos = atomicAdd(&scur[s >> 8], 1);
        spack[qos] = (unsigned char)(s & 255);
    }
}

// ---------------- pass 2a: per-region LDS counting sort -> exact CSR ----------------
__global__ __launch_bounds__(1024) void region_sort_kernel(const int* __restrict__ epack,
                                                           const int* __restrict__ rstart,
                                                           int* __restrict__ csrc,
                                                           int* __restrict__ row_start,
                                                           float* __restrict__ r_in,
                                                           int N, int NR, int E) {
    __shared__ int cnt[RN];
    __shared__ int cur[RN];
    __shared__ int wsum[16];
    const int r = blockIdx.x, tid = threadIdx.x;
    const int lane = tid & 63, w = tid >> 6;
    const int s0 = rstart[r], s1 = rstart[r + 1];
    if (tid < RN) cnt[tid] = 0;
    __syncthreads();
    for (int e = s0 + tid; e < s1; e += 1024)
        atomicAdd(&cnt[epack[e] >> 17], 1);
    __syncthreads();
    int cv = (tid < RN) ? cnt[tid] : 0;
    int x = cv;
    #pragma unroll
    for (int d = 1; d < 64; d <<= 1) {
        int t = __shfl_up(x, d, 64);
        if (lane >= d) x += t;
    }
    if (lane == 63 && w < 4) wsum[w] = x;
    __syncthreads();
    if (tid < RN) {
        int woff = 0;
        for (int i = 0; i < w; i++) woff += wsum[i];
        int start = s0 + x - cv + woff;
        cur[tid] = start;
        int node = r * RN + tid;
        if (node < N) {
            row_start[node] = start;
            r_in[node] = rsqrtf((float)max(cv, 1));
        }
    }
    if (r == NR - 1 && tid == 0) row_start[N] = E;
    __syncthreads();
    for (int e = s0 + tid; e < s1; e += 1024) {
        int pk = epack[e];
        int pos = atomicAdd(&cur[pk >> 17], 1);
        csrc[pos] = pk & 0x1FFFF;
    }
}

// ---------------- pass 2b: per-region byte histogram -> r_out ----------------
__global__ __launch_bounds__(256) void rout2_kernel(const unsigned char* __restrict__ spack,
                                                    const int* __restrict__ sstart,
                                                    float* __restrict__ r_out, int N) {
    __shared__ int cnt[RN];
    const int r = blockIdx.x, tid = threadIdx.x;
    const int s0 = sstart[r], s1 = sstart[r + 1];
    cnt[tid] = 0;
    __syncthreads();
    for (int e = s0 + tid; e < s1; e += 256)
        atomicAdd(&cnt[spack[e]], 1);
    __syncthreads();
    int node = r * RN + tid;
    if (node < N) r_out[node] = rsqrtf((float)max(cnt[tid], 1));
}

// ---------------- aggregation: one wave per node, CSR gather (fp16 rows) ----------------
// z1h[v] = fp16( r_in[v] * sum_e Xs[csrc[e]] )
__global__ __launch_bounds__(256) void agg128_kernel(const __half* __restrict__ Xs,
                                                     const float* __restrict__ r_in,
                                                     const int* __restrict__ rs,
                                                     const int* __restrict__ csrc,
                                                     __half* __restrict__ Z, int N) {
    const int lane = threadIdx.x & 63, wv = threadIdx.x >> 6;
    int v = blockIdx.x * 4 + wv;
    if (v >= N) return;
    int s0 = rs[v], s1 = rs[v + 1];
    float ax = 0.f, ay = 0.f;
    int e = s0;
    for (; e + 16 <= s1; e += 16) {
        int idx[16];
        #pragma unroll
        for (int u = 0; u < 16; u++) idx[u] = csrc[e + u];
        __half2 t[16];
        #pragma unroll
        for (int u = 0; u < 16; u++)
            t[u] = ((const __half2*)(Xs + (size_t)idx[u] * FD))[lane];
        #pragma unroll
        for (int u = 0; u < 16; u++) {
            float2 f = __half22float2(t[u]);
            ax += f.x; ay += f.y;
        }
    }
    for (; e + 4 <= s1; e += 4) {
        int idx[4];
        #pragma unroll
        for (int u = 0; u < 4; u++) idx[u] = csrc[e + u];
        __half2 t[4];
        #pragma unroll
        for (int u = 0; u < 4; u++)
            t[u] = ((const __half2*)(Xs + (size_t)idx[u] * FD))[lane];
        #pragma unroll
        for (int u = 0; u < 4; u++) {
            float2 f = __half22float2(t[u]);
            ax += f.x; ay += f.y;
        }
    }
    for (; e < s1; e++) {
        float2 f = __half22float2(((const __half2*)(Xs + (size_t)csrc[e] * FD))[lane]);
        ax += f.x; ay += f.y;
    }
    float ri = r_in[v];
    ((__half2*)(Z + (size_t)v * FD))[lane] = __floats2half2_rn(ax * ri, ay * ri);
}

// 2 nodes per wave, 32 lanes x half2 each (4B/lane loads, 128B/row)
__global__ __launch_bounds__(256) void agg64_kernel(const __half* __restrict__ T,
                                                    const float* __restrict__ r_in,
                                                    const int* __restrict__ rs,
                                                    const int* __restrict__ csrc,
                                                    const float* __restrict__ bc,
                                                    float* __restrict__ out, int N) {
    const int tid = threadIdx.x;
    const int lane = tid & 63, wv = tid >> 6;
    const int hf = lane >> 5, l32 = lane & 31;
    int v = blockIdx.x * 8 + wv * 2 + hf;
    if (v >= N) return;
    int s0 = rs[v], s1 = rs[v + 1];
    float ax = 0.f, ay = 0.f;
    int e = s0;
    for (; e + 8 <= s1; e += 8) {
        int idx[8];
        #pragma unroll
        for (int u = 0; u < 8; u++) idx[u] = csrc[e + u];
        __half2 t[8];
        #pragma unroll
        for (int u = 0; u < 8; u++)
            t[u] = ((const __half2*)(T + (size_t)idx[u] * OD))[l32];
        #pragma unroll
        for (int u = 0; u < 8; u++) {
            float2 f = __half22float2(t[u]);
            ax += f.x; ay += f.y;
        }
    }
    for (; e < s1; e++) {
        float2 f = __half22float2(((const __half2*)(T + (size_t)csrc[e] * OD))[l32]);
        ax += f.x; ay += f.y;
    }
    float ri = r_in[v];
    float2 o;
    o.x = ax * ri + bc[l32 * 2];
    o.y = ay * ri + bc[l32 * 2 + 1];
    ((float2*)(out + (size_t)v * OD))[l32] = o;
}

// ---------------- MFMA GEMM 1: y1h = fp16(relu(z1h@W1h + b1) * r_out) ----------------
__global__ __launch_bounds__(256) void gemm1_mfma_kernel(const __half* __restrict__ Ah,
                                                         const __half* __restrict__ Bh,
                                                         const float* __restrict__ b1,
                                                         const float* __restrict__ rowscale,
                                                         __half* __restrict__ Ch,
                                                         int M, int ntiles) {
    const int w = threadIdx.x >> 6, lane = threadIdx.x & 63;
    const int l15 = lane & 15, quad = lane >> 4;
    const _Float16* B = (const _Float16*)Bh;

    f16x8 bfrag[2][4];
    #pragma unroll
    for (int nt = 0; nt < 2; nt++) {
        int col = 32 * w + 16 * nt + l15;
        #pragma unroll
        for (int kk = 0; kk < 4; kk++) {
            int kb = kk * 32 + quad * 8;
            f16x8 bf;
            #pragma unroll
            for (int j = 0; j < 8; j++) bf[j] = B[(size_t)(kb + j) * FD + col];
            bfrag[nt][kk] = bf;
        }
    }

    for (int t = blockIdx.x; t < ntiles; t += gridDim.x) {
        int row0 = t * 16;
        const _Float16* Arow = (const _Float16*)Ah + (size_t)(row0 + l15) * FD + quad * 8;
        f16x8 afrag[4];
        #pragma unroll
        for (int kk = 0; kk < 4; kk++) afrag[kk] = *(const f16x8*)(Arow + kk * 32);
        f32x4 acc0 = {0.f, 0.f, 0.f, 0.f};
        f32x4 acc1 = {0.f, 0.f, 0.f, 0.f};
        #pragma unroll
        for (int kk = 0; kk < 4; kk++) {
            acc0 = __builtin_amdgcn_mfma_f32_16x16x32_f16(afrag[kk], bfrag[0][kk], acc0, 0, 0, 0);
            acc1 = __builtin_amdgcn_mfma_f32_16x16x32_f16(afrag[kk], bfrag[1][kk], acc1, 0, 0, 0);
        }
        int c0 = 32 * w + l15, c1 = c0 + 16;
        float bb0 = b1[c0], bb1 = b1[c1];
        #pragma unroll
        for (int r = 0; r < 4; r++) {
            int row = row0 + quad * 4 + r;
            if (row < M) {
                float rsc = rowscale[row];
                Ch[(size_t)row * FD + c0] = __float2half(fmaxf(acc0[r] + bb0, 0.f) * rsc);
                Ch[(size_t)row * FD + c1] = __float2half(fmaxf(acc1[r] + bb1, 0.f) * rsc);
            }
        }
    }
}

// ---------------- MFMA GEMM 2: tbuf = fp16(y1h @ Wch) (N=64) ----------------
__global__ __launch_bounds__(256) void gemm2_mfma_kernel(const __half* __restrict__ Ah,
                                                         const __half* __restrict__ Bh,
                                                         __half* __restrict__ Ch,
                                                         int M, int ntiles) {
    const int w = threadIdx.x >> 6, lane = threadIdx.x & 63;
    const int l15 = lane & 15, quad = lane >> 4;
    const _Float16* B = (const _Float16*)Bh;

    f16x8 bfrag[4];
    int col = 16 * w + l15;
    #pragma unroll
    for (int kk = 0; kk < 4; kk++) {
        int kb = kk * 32 + quad * 8;
        f16x8 bf;
        #pragma unroll
        for (int j = 0; j < 8; j++) bf[j] = B[(size_t)(kb + j) * OD + col];
        bfrag[kk] = bf;
    }

    for (int t = blockIdx.x; t < ntiles; t += gridDim.x) {
        int row0 = t * 16;
        const _Float16* Arow = (const _Float16*)Ah + (size_t)(row0 + l15) * FD + quad * 8;
        f16x8 afrag[4];
        #pragma unroll
        for (int kk = 0; kk < 4; kk++) afrag[kk] = *(const f16x8*)(Arow + kk * 32);
        f32x4 acc = {0.f, 0.f, 0.f, 0.f};
        #pragma unroll
        for (int kk = 0; kk < 4; kk++)
            acc = __builtin_amdgcn_mfma_f32_16x16x32_f16(afrag[kk], bfrag[kk], acc, 0, 0, 0);
        #pragma unroll
        for (int r = 0; r < 4; r++) {
            int row = row0 + quad * 4 + r;
            if (row < M)
                Ch[(size_t)row * OD + col] = __float2half(acc[r]);
        }
    }
}

// ---------------- fold: W1h = fp16(W1); Wch = fp16(W2@Wf); bc = b2@Wf + bf ----------------
__global__ void fold_kernel(const float* __restrict__ W2, const float* __restrict__ Wf,
                            const float* __restrict__ b2, const float* __restrict__ bf,
                            const float* __restrict__ W1,
                            __half* __restrict__ W1h, __half* __restrict__ Wch,
                            float* __restrict__ bc) {
    int idx = blockIdx.x * 256 + threadIdx.x;
    if (idx < FD * FD) W1h[idx] = __float2half(W1[idx]);
    if (idx < FD * OD) {
        int i = idx / OD, j = idx % OD;
        float s = 0.f;
        for (int k = 0; k < FD; k++) s += W2[i * FD + k] * Wf[k * OD + j];
        Wch[idx] = __float2half(s);
    }
    if (idx < OD) {
        float s = bf[idx];
        for (int k = 0; k < FD; k++) s += b2[k] * Wf[k * OD + idx];
        bc[idx] = s;
    }
}

// ---------------- launch ----------------
extern "C" void kernel_launch(void* const* d_in, const int* in_sizes, int n_in,
                              void* d_out, int out_size, void* d_ws, size_t ws_size,
                              hipStream_t stream) {
    const float* in_feat = (const float*)d_in[0];
    const int*   src     = (const int*)d_in[1];
    const int*   dst     = (const int*)d_in[2];
    const float* W1      = (const float*)d_in[3];
    const float* b1      = (const float*)d_in[4];
    const float* W2      = (const float*)d_in[5];
    const float* b2      = (const float*)d_in[6];
    const float* Wf      = (const float*)d_in[7];
    const float* bf      = (const float*)d_in[8];
    float* out = (float*)d_out;

    const int N = in_sizes[0] / FD;        // 50000
    const int E = in_sizes[1];             // 1600000
    const int NR = (N + RN - 1) / RN;      // 196 (<= NRMAX)
    const int CS = (((E + CHUNKS - 1) / CHUNKS) + 3) & ~3;  // 4-aligned for int4

    char* ws = (char*)d_ws;
    size_t off = 0;
    auto alloc = [&](size_t bytes) -> void* {
        void* p = ws + off;
        off += (bytes + 255) / 256 * 256;
        return p;
    };
    // spack (1.6 MB) + epack (6.4 MB) adjacent; both dead before gemm2 writes
    // tbuf (N*OD*2 = 6.4 MB) which aliases them.
    unsigned char* spack = (unsigned char*)alloc((size_t)E);
    int*    epack   = (int*)alloc((size_t)E * 4);
    __half* tbuf    = (__half*)spack;
    float*  r_out   = (float*)alloc((size_t)N * 4);
    float*  r_in    = (float*)alloc((size_t)N * 4);
    int*    hist_g  = (int*)alloc((size_t)CHUNKS * NR * 4);
    int*    hist_gs = (int*)alloc((size_t)CHUNKS * NR * 4);
    int*    cursor  = (int*)alloc((size_t)CHUNKS * NR * 4);
    int*    scursor = (int*)alloc((size_t)CHUNKS * NR * 4);
    int*    rstart  = (int*)alloc((size_t)(NR + 1) * 4);
    int*    sstart  = (int*)alloc((size_t)(NR + 1) * 4);
    int*    csrc    = (int*)alloc((size_t)E * 4);
    int*    row_start = (int*)alloc((size_t)(N + 1) * 4);
    __half* z1h     = (__half*)alloc((size_t)N * FD * 2);
    __half* y1h     = (__half*)alloc((size_t)N * FD * 2);
    __half* Xs      = (__half*)alloc((size_t)N * FD * 2);
    __half* W1h     = (__half*)alloc((size_t)FD * FD * 2);
    __half* Wch     = (__half*)alloc((size_t)FD * OD * 2);
    float*  bc      = (float*)alloc((size_t)OD * 4);
    (void)ws_size; (void)n_in; (void)out_size;

    const int ntiles = (N + 15) / 16;      // 3125
    const int gemmgrid = ntiles < 1024 ? ntiles : 1024;

    // exact dst-sort + src-degree count, zero per-edge global atomics:
    // dual region partition (pass 1) then per-region LDS passes (pass 2).
    region_hist_kernel<<<CHUNKS, 1024, 0, stream>>>(src, dst, hist_g, hist_gs, E, NR, CS);
    region_scan_kernel<<<1, 1024, 0, stream>>>(hist_g, hist_gs, rstart, cursor, sstart, scursor, NR, E);
    partition_kernel<<<CHUNKS, 1024, 0, stream>>>(src, dst, cursor, scursor, epack, spack, E, NR, CS);
    region_sort_kernel<<<NR, 1024, 0, stream>>>(epack, rstart, csrc, row_start, r_in, N, NR, E);
    rout2_kernel<<<NR, 256, 0, stream>>>(spack, sstart, r_out, N);

    // fold weights (fp16) + combined final bias
    fold_kernel<<<(FD * FD + 255) / 256, 256, 0, stream>>>(W2, Wf, b2, bf, W1, W1h, Wch, bc);

    // layer 1: Xs = half(r_out*x) ; z1h = half(r_in*Agg(Xs))
    prescale_kernel<<<(N * 32 + 255) / 256, 256, 0, stream>>>(in_feat, r_out, Xs, N * 32);
    agg128_kernel<<<(N + 3) / 4, 256, 0, stream>>>(Xs, r_in, row_start, csrc, z1h, N);

    // MFMA GEMMs: y1h = relu(z1h@W1h+b1)*r_out ; tbuf = y1h@Wch
    gemm1_mfma_kernel<<<gemmgrid, 256, 0, stream>>>(z1h, W1h, b1, r_out, y1h, N, ntiles);
    gemm2_mfma_kernel<<<gemmgrid, 256, 0, stream>>>(y1h, Wch, tbuf, N, ntiles);

    // final: out = r_in*Agg(tbuf) + bc
    agg64_kernel<<<(N + 7) / 8, 256, 0, stream>>>(tbuf, r_in, row_start, csrc, bc, out, N);
}